// Round 2
// baseline (1139.533 us; speedup 1.0000x reference)
//
#include <hip/hip_runtime.h>
#include <math.h>
#include <stdint.h>

#define T_ 800
#define B_ 32
#define D_ 440
#define DP_ 448      // D padded to mult of 64 (448 = 7*64)
#define H_ 1024
#define L_ 4
#define O_ 2000
#define OP_ 2048     // O padded to mult of 256
#define EPS_ 1e-5f
#define M_ (T_ * B_)   // 25600
#define BH_ (B_ * H_)  // 32768
#define NC_ 16
#define TC_ (T_ / NC_) // 50

// 256x256x64 8-wave 4-phase GEMM geometry
#define BM2 256
#define BN2 256
#define BK2 64

typedef __attribute__((ext_vector_type(8))) short bf16x8;
typedef __attribute__((ext_vector_type(4))) float f32x4;

__device__ inline float b2f(unsigned short u) {
    union { unsigned int i; float f; } v; v.i = ((unsigned int)u) << 16; return v.f;
}
__device__ inline unsigned short f2b(float f) {   // RNE bf16 (finite only)
    unsigned int x = __float_as_uint(f);
    return (unsigned short)((x + 0x7FFFu + ((x >> 16) & 1u)) >> 16);
}

// ---------------------------------------------------------------------------
// BN fold with dst padding: y = x*scale + bias; i >= nsrc -> 0
// ---------------------------------------------------------------------------
__global__ void bn_prep(const float* __restrict__ g, const float* __restrict__ b,
                        const float* __restrict__ m, const float* __restrict__ v,
                        float* __restrict__ scale, float* __restrict__ bias,
                        int nsrc, int ndst)
{
    int i = blockIdx.x * 256 + threadIdx.x;
    if (i >= ndst) return;
    if (i < nsrc) {
        float s = g[i] * rsqrtf(v[i] + EPS_);
        scale[i] = s;
        bias[i] = fmaf(-m[i], s, b[i]);
    } else {
        scale[i] = 0.f;
        bias[i] = 0.f;
    }
}

// ---------------------------------------------------------------------------
// fp32 [Rs x Cs] -> bf16 [Rd x Cd], 8 cols per thread.
// Requires Cs%8==0, Cd%8==0, 16B-aligned rows.  r>=Rs or c>=Cs -> 0.
// ---------------------------------------------------------------------------
__global__ void cvt_pad8(const float* __restrict__ src, unsigned short* __restrict__ dst,
                         int Rs, int Cs, int Cd, int total8)
{
    int i = blockIdx.x * 256 + threadIdx.x;
    if (i >= total8) return;
    const int c8 = Cd >> 3;
    int r = i / c8, c = (i - r * c8) << 3;
    ushort4 lo, hi;
    if (r < Rs && c < Cs) {
        const float4 a = *(const float4*)(src + (size_t)r * Cs + c);
        const float4 b = *(const float4*)(src + (size_t)r * Cs + c + 4);
        lo = make_ushort4(f2b(a.x), f2b(a.y), f2b(a.z), f2b(a.w));
        hi = make_ushort4(f2b(b.x), f2b(b.y), f2b(b.z), f2b(b.w));
    } else {
        lo = make_ushort4(0, 0, 0, 0);
        hi = make_ushort4(0, 0, 0, 0);
    }
    unsigned short* d = dst + (size_t)r * Cd + c;
    *(ushort4*)d = lo;
    *(ushort4*)(d + 4) = hi;
}

// ---------------------------------------------------------------------------
// bf16 NT GEMM, 256x256x64 tiles, 8 waves (2M x 4N), phase-interleaved:
//   - per K-tile: 4 phases, each {ds_reads | stage 1 half-tile | barrier |
//     lgkmcnt(0) | setprio(1) 16xMFMA setprio(0) | barrier}
//   - counted s_waitcnt vmcnt(4) ONCE per K-tile (never 0 in steady state):
//     stage order P0:Ah1(t+1) P1:Bh1(t+1) P2:Bh0(t+2) P3:Ah0(t+2) keeps the
//     2 newest half-tile stages in flight across the tile boundary; the
//     tile-boundary vmcnt(4) drains exactly through P1's loads, so all of
//     tile t+1 has landed before iteration t+1 reads it.
//   - LDS XOR swizzle elem ^= (row&7)<<3 (full 3-bit permutation: fragment
//     ds_read_b128 hits every bank exactly 8 words/wave — conflict-free),
//     realized as linear global_load_lds dest + inverse-swizzled GLOBAL src,
//     swizzled ds_read addresses (both-sides rule).
//   - B tiles column-interleaved (LDS slot s -> global col
//     n0+(s>>6)*64+(s&15)*4+((s>>4)&3)) so one lane's 4 ni values are 4
//     consecutive columns -> ushort4 stores.
// mode 0: n<H -> z=sigmoid(bn), else c=relu(bn); bf16 [M x H]
// mode 1: logits bf16 [M x OP_], bn affine only
// grid: 800 blocks linear; bx=blockIdx&7 (N tile) so XCD x owns B-panel x.
// ---------------------------------------------------------------------------

#define GLDS16(src, dst) __builtin_amdgcn_global_load_lds( \
    (const __attribute__((address_space(1))) unsigned int*)(src), \
    (__attribute__((address_space(3))) unsigned int*)(dst), 16, 0, 0)

#define SBAR() __builtin_amdgcn_s_barrier()
#define LGKM0() do { asm volatile("s_waitcnt lgkmcnt(0)" ::: "memory"); \
                     __builtin_amdgcn_sched_barrier(0); } while (0)

__global__ __launch_bounds__(512, 2) void gemm_bf16(
    const unsigned short* __restrict__ A, const unsigned short* __restrict__ Wt,
    int K, int mode,
    unsigned short* __restrict__ zout, unsigned short* __restrict__ cout,
    const float* __restrict__ zscale, const float* __restrict__ zbias,
    const float* __restrict__ cscale, const float* __restrict__ cbias,
    unsigned short* __restrict__ fout,
    const float* __restrict__ fscale, const float* __restrict__ fbias)
{
    // [buf][half][128 rows x 64 cols]  -> 64 KB A + 64 KB B = 128 KB
    __shared__ unsigned short As[2][2][128 * 64];
    __shared__ unsigned short Bs[2][2][128 * 64];

    const int tid = threadIdx.x;
    const int lane = tid & 63;
    const int wid = tid >> 6;            // 0..7
    const int wm = wid >> 2;             // 0..1  M half (rows wm*128..)
    const int wn = wid & 3;              // 0..3  N quarter (cols wn*64..)
    const int wn1 = wn & 1;

    const int bx = blockIdx.x & 7;       // N tile
    const int by = blockIdx.x >> 3;      // M tile
    const int m0 = by * BM2;
    const int n0 = bx * BN2;

    // ---- staging source addresses (inverse-swizzled global cols) ----
    // thread covers LDS phys rows rl = (wid*2+i)*8 + (lane>>3), 16B at
    // within-row elem (lane&7)*8; source col elem = that ^ ((row&7)<<3).
    const int rl0 = (wid * 2 + 0) * 8 + (lane >> 3);
    const int rl1 = (wid * 2 + 1) * 8 + (lane >> 3);
    const int cswz = ((lane & 7) * 8) ^ ((lane >> 3) << 3);

    const unsigned short* aS00 = A + (size_t)(m0 + rl0) * K + cswz;        // half 0, i=0
    const unsigned short* aS01 = A + (size_t)(m0 + rl1) * K + cswz;        // half 0, i=1
    const unsigned short* aS10 = A + (size_t)(m0 + 128 + rl0) * K + cswz;  // half 1, i=0
    const unsigned short* aS11 = A + (size_t)(m0 + 128 + rl1) * K + cswz;

    // B column interleave: LDS slot s -> global col
    const int gc00 = n0 + ((rl0 >> 6) << 6) + (rl0 & 15) * 4 + ((rl0 >> 4) & 3);
    const int gc01 = n0 + ((rl1 >> 6) << 6) + (rl1 & 15) * 4 + ((rl1 >> 4) & 3);
    const int s10 = 128 + rl0, s11 = 128 + rl1;
    const int gc10 = n0 + ((s10 >> 6) << 6) + (s10 & 15) * 4 + ((s10 >> 4) & 3);
    const int gc11 = n0 + ((s11 >> 6) << 6) + (s11 & 15) * 4 + ((s11 >> 4) & 3);
    const unsigned short* bS00 = Wt + (size_t)gc00 * K + cswz;
    const unsigned short* bS01 = Wt + (size_t)gc01 * K + cswz;
    const unsigned short* bS10 = Wt + (size_t)gc10 * K + cswz;
    const unsigned short* bS11 = Wt + (size_t)gc11 * K + cswz;

    const int ls0 = (wid * 2 + 0) * 512;   // LDS dest slot (elements), wave-uniform
    const int ls1 = (wid * 2 + 1) * 512;

    // ---- fragment read addressing (swizzled) ----
    const int fr = lane & 15;
    const int q = lane >> 4;
    const int rxor = (fr & 7) << 3;
    const int c0 = (q * 8) ^ rxor;          // k-slice 0
    const int c1 = (32 + q * 8) ^ rxor;     // k-slice 1

    f32x4 acc[8][4];
    #pragma unroll
    for (int i = 0; i < 8; i++)
        #pragma unroll
        for (int j = 0; j < 4; j++)
            acc[i][j] = (f32x4){0.f, 0.f, 0.f, 0.f};

    bf16x8 af[4][2];    // A frags, reused mh0 then mh1
    bf16x8 bfv[4][2];   // B frags, all 4 live across the tile

    const int nT = K / BK2;

    // ---- prologue: tile0 all 4 halves, then Bh0(1), Ah0(1) ----
    GLDS16(aS00, &As[0][0][ls0]); GLDS16(aS01, &As[0][0][ls1]);
    GLDS16(aS10, &As[0][1][ls0]); GLDS16(aS11, &As[0][1][ls1]);
    GLDS16(bS00, &Bs[0][0][ls0]); GLDS16(bS01, &Bs[0][0][ls1]);
    GLDS16(bS10, &Bs[0][1][ls0]); GLDS16(bS11, &Bs[0][1][ls1]);
    if (nT > 1) {
        GLDS16(bS00 + BK2, &Bs[1][0][ls0]); GLDS16(bS01 + BK2, &Bs[1][0][ls1]);
        GLDS16(aS00 + BK2, &As[1][0][ls0]); GLDS16(aS01 + BK2, &As[1][0][ls1]);
    }
    asm volatile("s_waitcnt vmcnt(4)" ::: "memory");
    SBAR();

#define READ_A(MOFF) do { _Pragma("unroll") \
    for (int m_ = 0; m_ < 4; ++m_) { \
        af[m_][0] = *(const bf16x8*)(Ac + ((MOFF + m_) * 16 + fr) * 64 + c0); \
        af[m_][1] = *(const bf16x8*)(Ac + ((MOFF + m_) * 16 + fr) * 64 + c1); \
    } } while (0)

#define READ_B(NOFF) do { _Pragma("unroll") \
    for (int n_ = 0; n_ < 2; ++n_) { \
        bfv[NOFF + n_][0] = *(const bf16x8*)(Bc + (wn1 * 64 + (NOFF + n_) * 16 + fr) * 64 + c0); \
        bfv[NOFF + n_][1] = *(const bf16x8*)(Bc + (wn1 * 64 + (NOFF + n_) * 16 + fr) * 64 + c1); \
    } } while (0)

#define MFMA16(MBASE, NBASE) do { \
    __builtin_amdgcn_s_setprio(1); \
    _Pragma("unroll") \
    for (int m_ = 0; m_ < 4; ++m_) \
        _Pragma("unroll") \
        for (int n_ = 0; n_ < 2; ++n_) \
            _Pragma("unroll") \
            for (int ks_ = 0; ks_ < 2; ++ks_) \
                acc[MBASE + m_][NBASE + n_] = __builtin_amdgcn_mfma_f32_16x16x32_bf16( \
                    af[m_][ks_], bfv[NBASE + n_][ks_], acc[MBASE + m_][NBASE + n_], 0, 0, 0); \
    __builtin_amdgcn_s_setprio(0); \
} while (0)

    for (int t = 0; t < nT; ++t) {
        const int cur = t & 1, nxt = cur ^ 1;
        const unsigned short* Ac = &As[cur][wm][0];
        const unsigned short* Bc = &Bs[cur][wn >> 1][0];
        const int k1 = (t + 1) * BK2;
        const int k2 = (t + 2) * BK2;

        // ---- phase 0: (mh0,nh0); reads A0-3 + B0-1; stage Ah1(t+1)
        READ_A(0);
        READ_B(0);
        if (t + 1 < nT) {
            GLDS16(aS10 + k1, &As[nxt][1][ls0]);
            GLDS16(aS11 + k1, &As[nxt][1][ls1]);
        }
        SBAR();
        LGKM0();
        MFMA16(0, 0);
        SBAR();

        // ---- phase 1: (mh0,nh1); reads B2-3; stage Bh1(t+1)
        READ_B(2);
        if (t + 1 < nT) {
            GLDS16(bS10 + k1, &Bs[nxt][1][ls0]);
            GLDS16(bS11 + k1, &Bs[nxt][1][ls1]);
        }
        SBAR();
        LGKM0();
        MFMA16(0, 2);
        SBAR();

        // ---- phase 2: (mh1,nh1); reads A4-7; stage Bh0(t+2) (old reads done P1)
        READ_A(4);
        if (t + 2 < nT) {
            GLDS16(bS00 + k2, &Bs[cur][0][ls0]);
            GLDS16(bS01 + k2, &Bs[cur][0][ls1]);
        }
        SBAR();
        LGKM0();
        MFMA16(4, 2);
        SBAR();

        // ---- phase 3: (mh1,nh0); no reads; stage Ah0(t+2) (old reads done P2)
        if (t + 2 < nT) {
            GLDS16(aS00 + k2, &As[cur][0][ls0]);
            GLDS16(aS01 + k2, &As[cur][0][ls1]);
        }
        SBAR();
        MFMA16(4, 0);
        if (t + 2 < nT) {
            asm volatile("s_waitcnt vmcnt(4)" ::: "memory");
        } else {
            asm volatile("s_waitcnt vmcnt(0)" ::: "memory");
        }
        SBAR();
    }

#undef READ_A
#undef READ_B
#undef MFMA16

    // ---- epilogue ----
    const int colb = n0 + wn * 64 + fr * 4;      // 4 consecutive global cols
    const int rbase = m0 + wm * 128 + q * 4;

    if (mode == 0) {
        const bool isz = (n0 < H_);
        const float* sc = isz ? zscale : cscale;
        const float* bi = isz ? zbias : cbias;
        unsigned short* dst = isz ? zout : cout;
        const int npb = isz ? colb : colb - H_;
        const float4 s4 = *(const float4*)(sc + npb);
        const float4 b4 = *(const float4*)(bi + npb);
        #pragma unroll
        for (int m = 0; m < 8; ++m)
            #pragma unroll
            for (int r = 0; r < 4; ++r) {
                const int mm = rbase + m * 16 + r;
                float v0 = fmaf(acc[m][0][r], s4.x, b4.x);
                float v1 = fmaf(acc[m][1][r], s4.y, b4.y);
                float v2 = fmaf(acc[m][2][r], s4.z, b4.z);
                float v3 = fmaf(acc[m][3][r], s4.w, b4.w);
                if (isz) {
                    v0 = __builtin_amdgcn_rcpf(1.f + __expf(-v0));
                    v1 = __builtin_amdgcn_rcpf(1.f + __expf(-v1));
                    v2 = __builtin_amdgcn_rcpf(1.f + __expf(-v2));
                    v3 = __builtin_amdgcn_rcpf(1.f + __expf(-v3));
                } else {
                    v0 = fmaxf(v0, 0.f); v1 = fmaxf(v1, 0.f);
                    v2 = fmaxf(v2, 0.f); v3 = fmaxf(v3, 0.f);
                }
                ushort4 pk = make_ushort4(f2b(v0), f2b(v1), f2b(v2), f2b(v3));
                *(ushort4*)(dst + (size_t)mm * H_ + npb) = pk;
            }
    } else {
        const float4 s4 = *(const float4*)(fscale + colb);
        const float4 b4 = *(const float4*)(fbias + colb);
        #pragma unroll
        for (int m = 0; m < 8; ++m)
            #pragma unroll
            for (int r = 0; r < 4; ++r) {
                const int mm = rbase + m * 16 + r;
                ushort4 pk = make_ushort4(
                    f2b(fmaf(acc[m][0][r], s4.x, b4.x)),
                    f2b(fmaf(acc[m][1][r], s4.y, b4.y)),
                    f2b(fmaf(acc[m][2][r], s4.z, b4.z)),
                    f2b(fmaf(acc[m][3][r], s4.w, b4.w)));
                *(ushort4*)(fout + (size_t)mm * OP_ + colb) = pk;
            }
    }
}

// ---------------------------------------------------------------------------
// Scan pass 1: per-chunk (H0, P), h_in = 0.  2 h's per thread (4B loads).
// Launched with gridDim.y = NC_-1 (last chunk's state is never consumed).
// ---------------------------------------------------------------------------
__global__ __launch_bounds__(256) void scan_pass1(
    const unsigned short* __restrict__ z, const unsigned short* __restrict__ c,
    float* __restrict__ H0, float* __restrict__ P)
{
    const int k = blockIdx.y;
    const int e2 = blockIdx.x * 256 + threadIdx.x;   // pair index < BH_/2
    float h0 = 0.f, h1 = 0.f, p0 = 1.f, p1 = 1.f;
    size_t off = ((size_t)k * TC_ * BH_ + 2 * e2) >> 1;   // in uint units
    const unsigned int* z32 = (const unsigned int*)z;
    const unsigned int* c32 = (const unsigned int*)c;
    #pragma unroll 5
    for (int t = 0; t < TC_; ++t) {
        unsigned int zz = z32[off], cc = c32[off];
        float z0 = b2f((unsigned short)zz), z1 = b2f((unsigned short)(zz >> 16));
        float c0 = b2f((unsigned short)cc), c1 = b2f((unsigned short)(cc >> 16));
        h0 = fmaf(z0, h0 - c0, c0);  p0 *= z0;
        h1 = fmaf(z1, h1 - c1, c1);  p1 *= z1;
        off += BH_ / 2;
    }
    *(float2*)(H0 + (size_t)k * BH_ + 2 * e2) = make_float2(h0, h1);
    *(float2*)(P  + (size_t)k * BH_ + 2 * e2) = make_float2(p0, p1);
}

// ---------------------------------------------------------------------------
// Scan pass 2: fold prior chunk states (exact affine composition), rerun, write x.
// ---------------------------------------------------------------------------
__global__ __launch_bounds__(256) void scan_pass2(
    const unsigned short* __restrict__ z, const unsigned short* __restrict__ c,
    const float* __restrict__ H0, const float* __restrict__ P,
    unsigned short* __restrict__ x)
{
    const int k = blockIdx.y;
    const int e2 = blockIdx.x * 256 + threadIdx.x;
    float h0 = 0.f, h1 = 0.f;
    for (int j = 0; j < k; ++j) {     // k block-uniform: no divergence
        float2 pj = *(const float2*)(P  + (size_t)j * BH_ + 2 * e2);
        float2 hj = *(const float2*)(H0 + (size_t)j * BH_ + 2 * e2);
        h0 = fmaf(pj.x, h0, hj.x);
        h1 = fmaf(pj.y, h1, hj.y);
    }
    size_t off = ((size_t)k * TC_ * BH_ + 2 * e2) >> 1;
    const unsigned int* z32 = (const unsigned int*)z;
    const unsigned int* c32 = (const unsigned int*)c;
    unsigned int* x32 = (unsigned int*)x;
    #pragma unroll 5
    for (int t = 0; t < TC_; ++t) {
        unsigned int zz = z32[off], cc = c32[off];
        float z0 = b2f((unsigned short)zz), z1 = b2f((unsigned short)(zz >> 16));
        float c0 = b2f((unsigned short)cc), c1 = b2f((unsigned short)(cc >> 16));
        h0 = fmaf(z0, h0 - c0, c0);
        h1 = fmaf(z1, h1 - c1, c1);
        x32[off] = (unsigned int)f2b(h0) | ((unsigned int)f2b(h1) << 16);
        off += BH_ / 2;
    }
}

// ---------------------------------------------------------------------------
// row-wise log_softmax: bf16 logits [M x OP_] -> fp32 out [M x O_]
// ---------------------------------------------------------------------------
__global__ __launch_bounds__(256) void logsoftmax_kernel(
    const unsigned short* __restrict__ lg, float* __restrict__ out)
{
    const int row = blockIdx.x;
    const unsigned short* p = lg + (size_t)row * OP_;
    float* po = out + (size_t)row * O_;
    const int tid = threadIdx.x;

    float v[8];
    float mx = -1e30f;
    #pragma unroll
    for (int j = 0; j < 8; j++) {
        int col = tid + j * 256;
        v[j] = (col < O_) ? b2f(p[col]) : -1e30f;
        mx = fmaxf(mx, v[j]);
    }
    #pragma unroll
    for (int o = 32; o > 0; o >>= 1) mx = fmaxf(mx, __shfl_down(mx, o));
    __shared__ float smax[4];
    __shared__ float ssum[4];
    const int lane = tid & 63, wid = tid >> 6;
    if (lane == 0) smax[wid] = mx;
    __syncthreads();
    mx = fmaxf(fmaxf(smax[0], smax[1]), fmaxf(smax[2], smax[3]));

    float s = 0.f;
    #pragma unroll
    for (int j = 0; j < 8; j++) {
        int col = tid + j * 256;
        if (col < O_) s += expf(v[j] - mx);
    }
    #pragma unroll
    for (int o = 32; o > 0; o >>= 1) s += __shfl_down(s, o);
    if (lane == 0) ssum[wid] = s;
    __syncthreads();
    s = ssum[0] + ssum[1] + ssum[2] + ssum[3];
    const float lse = mx + logf(s);

    #pragma unroll
    for (int j = 0; j < 8; j++) {
        int col = tid + j * 256;
        if (col < O_) po[col] = v[j] - lse;
    }
}

// ---------------------------------------------------------------------------
extern "C" void kernel_launch(void* const* d_in, const int* in_sizes, int n_in,
                              void* d_out, int out_size, void* d_ws, size_t ws_size,
                              hipStream_t stream)
{
    (void)in_sizes; (void)n_in; (void)out_size; (void)ws_size;

    const float* xs    = (const float*)d_in[0];
    const float* w0    = (const float*)d_in[1];
    const float* wr    = (const float*)d_in[2];
    const float* bnz_g = (const float*)d_in[3];
    const float* bnz_b = (const float*)d_in[4];
    const float* bnz_m = (const float*)d_in[5];
    const float* bnz_v = (const float*)d_in[6];
    const float* bnc_g = (const float*)d_in[7];
    const float* bnc_b = (const float*)d_in[8];
    const float* bnc_m = (const float*)d_in[9];
    const float* bnc_v = (const float*)d_in[10];
    const float* wf    = (const float*)d_in[11];
    const float* bnf_g = (const float*)d_in[12];
    const float* bnf_b = (const float*)d_in[13];
    const float* bnf_m = (const float*)d_in[14];
    const float* bnf_v = (const float*)d_in[15];
    float* out = (float*)d_out;

    unsigned short* p = (unsigned short*)d_ws;
    unsigned short* xbuf  = p;  p += (size_t)M_ * H_;
    unsigned short* x0buf = p;  p += (size_t)M_ * DP_;
    unsigned short* zbuf  = p;  p += (size_t)M_ * H_;
    unsigned short* cbuf  = p;  p += (size_t)M_ * H_;
    unsigned short* w0p   = p;  p += (size_t)(2 * H_) * DP_;
    unsigned short* wrp   = p;  p += (size_t)(L_ - 1) * (2 * H_) * H_;
    unsigned short* wfp   = p;  p += (size_t)OP_ * H_;
    unsigned short* lbuf  = p;  p += (size_t)M_ * OP_;
    float* fp = (float*)p;
    float* zs = fp;  fp += L_ * H_;
    float* zb = fp;  fp += L_ * H_;
    float* cs = fp;  fp += L_ * H_;
    float* cb = fp;  fp += L_ * H_;
    float* fs = fp;  fp += OP_;
    float* fb = fp;  fp += OP_;
    float* sH0 = fp; fp += NC_ * BH_;
    float* sP  = fp;

    dim3 blk(256);
    bn_prep<<<(L_ * H_ + 255) / 256, blk, 0, stream>>>(bnz_g, bnz_b, bnz_m, bnz_v, zs, zb, L_ * H_, L_ * H_);
    bn_prep<<<(L_ * H_ + 255) / 256, blk, 0, stream>>>(bnc_g, bnc_b, bnc_m, bnc_v, cs, cb, L_ * H_, L_ * H_);
    bn_prep<<<(OP_ + 255) / 256, blk, 0, stream>>>(bnf_g, bnf_b, bnf_m, bnf_v, fs, fb, O_, OP_);

    {   // bf16 conversions with padding (all shapes satisfy Cs%8==0, 16B rows)
        int t0 = M_ * DP_ / 8;
        cvt_pad8<<<(t0 + 255) / 256, blk, 0, stream>>>(xs, x0buf, M_, D_, DP_, t0);
        int t1 = 2 * H_ * DP_ / 8;
        cvt_pad8<<<(t1 + 255) / 256, blk, 0, stream>>>(w0, w0p, 2 * H_, D_, DP_, t1);
        int t2 = (L_ - 1) * 2 * H_ * H_ / 8;
        cvt_pad8<<<(t2 + 255) / 256, blk, 0, stream>>>(wr, wrp, (L_ - 1) * 2 * H_, H_, H_, t2);
        int t3 = OP_ * H_ / 8;
        cvt_pad8<<<(t3 + 255) / 256, blk, 0, stream>>>(wf, wfp, O_, H_, H_, t3);
    }

    dim3 blk2(512);
    dim3 grid2((M_ / BM2) * ((2 * H_) / BN2));    // 100 * 8 = 800
    dim3 sgrid1(BH_ / 512, NC_ - 1);
    dim3 sgrid2(BH_ / 512, NC_);
    for (int layer = 0; layer < L_; ++layer) {
        const unsigned short* Ain = (layer == 0) ? x0buf : xbuf;
        const unsigned short* W   = (layer == 0) ? w0p : (wrp + (size_t)(layer - 1) * (2 * H_) * H_);
        const int K               = (layer == 0) ? DP_ : H_;
        gemm_bf16<<<grid2, blk2, 0, stream>>>(Ain, W, K, 0,
            zbuf, cbuf,
            zs + layer * H_, zb + layer * H_, cs + layer * H_, cb + layer * H_,
            nullptr, nullptr, nullptr);
        scan_pass1<<<sgrid1, blk, 0, stream>>>(zbuf, cbuf, sH0, sP);
        scan_pass2<<<sgrid2, blk, 0, stream>>>(zbuf, cbuf, sH0, sP, xbuf);
    }

    dim3 gridf((M_ / BM2) * (OP_ / BN2));         // 100 * 8 = 800
    gemm_bf16<<<gridf, blk2, 0, stream>>>(xbuf, wfp, H_, 1,
        nullptr, nullptr, nullptr, nullptr, nullptr, nullptr,
        lbuf, fs, fb);

    logsoftmax_kernel<<<M_, blk, 0, stream>>>(lbuf, out);
}

// Round 4
// 1120.994 us; speedup vs baseline: 1.0165x; 1.0165x over previous
//
#include <hip/hip_runtime.h>
#include <math.h>
#include <stdint.h>

#define T_ 800
#define B_ 32
#define D_ 440
#define DP_ 448      // D padded to mult of 32
#define H_ 1024
#define L_ 4
#define O_ 2000
#define OP_ 2048     // O padded to mult of 256
#define EPS_ 1e-5f
#define M_ (T_ * B_)   // 25600
#define BH_ (B_ * H_)  // 32768
#define NC_ 16
#define TC_ (T_ / NC_) // 50

// 128x256x32 4-wave GEMM geometry, 2 blocks/CU
#define BM2 128
#define BN2 256
#define BK2 32

typedef __attribute__((ext_vector_type(8))) short bf16x8;
typedef __attribute__((ext_vector_type(4))) float f32x4;

__device__ inline float b2f(unsigned short u) {
    union { unsigned int i; float f; } v; v.i = ((unsigned int)u) << 16; return v.f;
}
__device__ inline unsigned short f2b(float f) {   // RNE bf16 (finite only)
    unsigned int x = __float_as_uint(f);
    return (unsigned short)((x + 0x7FFFu + ((x >> 16) & 1u)) >> 16);
}

// ---------------------------------------------------------------------------
// BN fold with dst padding: y = x*scale + bias; i >= nsrc -> 0
// ---------------------------------------------------------------------------
__global__ void bn_prep(const float* __restrict__ g, const float* __restrict__ b,
                        const float* __restrict__ m, const float* __restrict__ v,
                        float* __restrict__ scale, float* __restrict__ bias,
                        int nsrc, int ndst)
{
    int i = blockIdx.x * 256 + threadIdx.x;
    if (i >= ndst) return;
    if (i < nsrc) {
        float s = g[i] * rsqrtf(v[i] + EPS_);
        scale[i] = s;
        bias[i] = fmaf(-m[i], s, b[i]);
    } else {
        scale[i] = 0.f;
        bias[i] = 0.f;
    }
}

// ---------------------------------------------------------------------------
// fp32 [Rs x Cs] -> bf16 [Rd x Cd], 8 cols per thread.
// ---------------------------------------------------------------------------
__global__ void cvt_pad8(const float* __restrict__ src, unsigned short* __restrict__ dst,
                         int Rs, int Cs, int Cd, int total8)
{
    int i = blockIdx.x * 256 + threadIdx.x;
    if (i >= total8) return;
    const int c8 = Cd >> 3;
    int r = i / c8, c = (i - r * c8) << 3;
    ushort4 lo, hi;
    if (r < Rs && c < Cs) {
        const float4 a = *(const float4*)(src + (size_t)r * Cs + c);
        const float4 b = *(const float4*)(src + (size_t)r * Cs + c + 4);
        lo = make_ushort4(f2b(a.x), f2b(a.y), f2b(a.z), f2b(a.w));
        hi = make_ushort4(f2b(b.x), f2b(b.y), f2b(b.z), f2b(b.w));
    } else {
        lo = make_ushort4(0, 0, 0, 0);
        hi = make_ushort4(0, 0, 0, 0);
    }
    unsigned short* d = dst + (size_t)r * Cd + c;
    *(ushort4*)d = lo;
    *(ushort4*)(d + 4) = hi;
}

// ---------------------------------------------------------------------------
// bf16 NT GEMM, 128x256x32 tiles, 4 waves (1M x 4N), 2 blocks/CU:
//   - two independent 4-wave barrier groups per CU overlap LDS-phase of one
//     block with MFMA-phase of the other (the 1-block/CU version measured
//     MfmaUtil 28%: LDS-read time and MFMA time ADD when barrier-locked).
//   - per K-tile: 2 phases {ds_reads | stage | bar | lgkm0 | 16 MFMA |
//     vmcnt(N) | bar}. Counted vmcnt(6), never 0 in steady state.
//     FIFO ledger/wave: P_A issues l(t+1) (A rows 64-127, 1 slot),
//     P_B issues e(t+2) (A rows 0-63 + all B, 5 slots).
//     P_A-end vmcnt(6) drains l(t) (needed by P_B reads);
//     P_B-end vmcnt(6) drains e(t+1) (needed by next P_A reads).
//     vmcnt wait precedes the barrier -> cross-wave staged data is visible.
//   - BK=32 rows (64B) make fragment ds_read_b128 conflict-free unswizzled
//     (bank group 16*(fr&1)+4q, 8 words/bank = floor), so stage dest and
//     reads are both linear (both-sides-or-neither rule trivially met).
//   - B tiles column-interleaved (LDS slot s -> global col
//     n0+(s>>6)*64+(s&15)*4+((s>>4)&3)) -> lane's 4 ni's are 4 consecutive
//     columns -> ushort4 stores. Same map/epilogue as the verified kernel.
// mode 0: n<H -> z=sigmoid(bn), else c=relu(bn); bf16 [M x H]
// mode 1: logits bf16 [M x OP_], bn affine only
// grid: 1600 blocks; bx=blockIdx&7 (N tile) so XCD x keeps B-panel x in L2.
// ---------------------------------------------------------------------------

#define GLDS16(src, dst) __builtin_amdgcn_global_load_lds( \
    (const __attribute__((address_space(1))) unsigned int*)(src), \
    (__attribute__((address_space(3))) unsigned int*)(dst), 16, 0, 0)

#define SBAR() __builtin_amdgcn_s_barrier()
#define LGKM0() do { asm volatile("s_waitcnt lgkmcnt(0)" ::: "memory"); \
                     __builtin_amdgcn_sched_barrier(0); } while (0)

__global__ __launch_bounds__(256, 2) void gemm_bf16(
    const unsigned short* __restrict__ A, const unsigned short* __restrict__ Wt,
    int K, int mode,
    unsigned short* __restrict__ zout, unsigned short* __restrict__ cout,
    const float* __restrict__ zscale, const float* __restrict__ zbias,
    const float* __restrict__ cscale, const float* __restrict__ cbias,
    unsigned short* __restrict__ fout,
    const float* __restrict__ fscale, const float* __restrict__ fbias)
{
    // A: [2 buf][128 rows x 32]  = 16 KB ; B: [2 buf][256 slots x 32] = 32 KB
    __shared__ unsigned short As[2][128 * 32];
    __shared__ unsigned short Bs[2][256 * 32];

    const int tid = threadIdx.x;
    const int lane = tid & 63;
    const int wid = tid >> 6;            // 0..3 = N quarter (cols wid*64..)

    const int bx = blockIdx.x & 7;       // N tile
    const int by = blockIdx.x >> 3;      // M tile
    const int m0 = by * BM2;
    const int n0 = bx * BN2;

    // ---- staging sources (linear; GLDS slot = 16 rows x 64B, lane l covers
    // row (l>>2), bytes (l&3)*16 of the 64B row) ----
    const int srow = lane >> 2;          // 0..15
    const int scol = (lane & 3) * 8;     // elem offset in 32-elem row

    const unsigned short* aE = A + (size_t)(m0 + wid * 16 + srow) * K + scol;       // A rows 0-63, slot wid
    const unsigned short* aL = A + (size_t)(m0 + 64 + wid * 16 + srow) * K + scol;  // A rows 64-127, slot 4+wid
    // B stage slots S = wid*4+i: gcol = n0 + wid*64 + srow*4 + i
    const unsigned short* bS0 = Wt + (size_t)(n0 + wid * 64 + srow * 4 + 0) * K + scol;
    const unsigned short* bS1 = Wt + (size_t)(n0 + wid * 64 + srow * 4 + 1) * K + scol;
    const unsigned short* bS2 = Wt + (size_t)(n0 + wid * 64 + srow * 4 + 2) * K + scol;
    const unsigned short* bS3 = Wt + (size_t)(n0 + wid * 64 + srow * 4 + 3) * K + scol;

    const int lsAE = wid * 512;          // LDS elem offsets (wave-uniform)
    const int lsAL = (4 + wid) * 512;
    const int lsB0 = (wid * 4 + 0) * 512;
    const int lsB1 = (wid * 4 + 1) * 512;
    const int lsB2 = (wid * 4 + 2) * 512;
    const int lsB3 = (wid * 4 + 3) * 512;

    // ---- fragment read addressing (linear) ----
    const int fr = lane & 15;
    const int q = lane >> 4;
    const int rdc = q * 8;

    f32x4 acc[8][4];
    #pragma unroll
    for (int i = 0; i < 8; i++)
        #pragma unroll
        for (int j = 0; j < 4; j++)
            acc[i][j] = (f32x4){0.f, 0.f, 0.f, 0.f};

    bf16x8 af[4], bfv[4];

    const int nT = K / BK2;

    // ---- prologue (FIFO order: e(0) [5], l(0) [1], e(1) [5]) ----
    GLDS16(aE,  &As[0][lsAE]);
    GLDS16(bS0, &Bs[0][lsB0]); GLDS16(bS1, &Bs[0][lsB1]);
    GLDS16(bS2, &Bs[0][lsB2]); GLDS16(bS3, &Bs[0][lsB3]);
    GLDS16(aL,  &As[0][lsAL]);
    if (nT > 1) {
        GLDS16(aE + BK2,  &As[1][lsAE]);
        GLDS16(bS0 + BK2, &Bs[1][lsB0]); GLDS16(bS1 + BK2, &Bs[1][lsB1]);
        GLDS16(bS2 + BK2, &Bs[1][lsB2]); GLDS16(bS3 + BK2, &Bs[1][lsB3]);
        asm volatile("s_waitcnt vmcnt(6)" ::: "memory");   // drain e(0)
    } else {
        asm volatile("s_waitcnt vmcnt(1)" ::: "memory");
    }
    SBAR();

#define MFMA16(MBASE) do { \
    __builtin_amdgcn_s_setprio(1); \
    _Pragma("unroll") \
    for (int m_ = 0; m_ < 4; ++m_) \
        _Pragma("unroll") \
        for (int n_ = 0; n_ < 4; ++n_) \
            acc[MBASE + m_][n_] = __builtin_amdgcn_mfma_f32_16x16x32_bf16( \
                af[m_], bfv[n_], acc[MBASE + m_][n_], 0, 0, 0); \
    __builtin_amdgcn_s_setprio(0); \
} while (0)

    for (int t = 0; t < nT; ++t) {
        const int cur = t & 1, nxt = cur ^ 1;
        const unsigned short* Ac = As[cur];
        const unsigned short* Bc = Bs[cur] + wid * (64 * 32);
        const int kL = (t + 1) * BK2;
        const int kE = (t + 2) * BK2;

        // ---- phase A: rows 0-63, all B; stage l(t+1) ----
        #pragma unroll
        for (int m_ = 0; m_ < 4; ++m_)
            af[m_] = *(const bf16x8*)(Ac + (m_ * 16 + fr) * 32 + rdc);
        #pragma unroll
        for (int n_ = 0; n_ < 4; ++n_)
            bfv[n_] = *(const bf16x8*)(Bc + (n_ * 16 + fr) * 32 + rdc);
        if (t + 1 < nT) {
            GLDS16(aL + kL, &As[nxt][lsAL]);
        }
        SBAR();
        LGKM0();
        MFMA16(0);
        if (t + 1 < nT) {                      // drain l(t) before P_B reads
            asm volatile("s_waitcnt vmcnt(6)" ::: "memory");
        } else {
            asm volatile("s_waitcnt vmcnt(0)" ::: "memory");
        }
        SBAR();

        // ---- phase B: rows 64-127; stage e(t+2) (buffer cur: rows 0-63 and
        // all B of cur were last read in phase A, done at its barrier) ----
        #pragma unroll
        for (int m_ = 0; m_ < 4; ++m_)
            af[m_] = *(const bf16x8*)(Ac + ((4 + m_) * 16 + fr) * 32 + rdc);
        if (t + 2 < nT) {
            GLDS16(aE + kE,  &As[cur][lsAE]);
            GLDS16(bS0 + kE, &Bs[cur][lsB0]); GLDS16(bS1 + kE, &Bs[cur][lsB1]);
            GLDS16(bS2 + kE, &Bs[cur][lsB2]); GLDS16(bS3 + kE, &Bs[cur][lsB3]);
        }
        SBAR();
        LGKM0();
        MFMA16(4);
        if (t + 2 < nT) {                      // drain e(t+1) before next P_A
            asm volatile("s_waitcnt vmcnt(6)" ::: "memory");
        } else if (t + 1 < nT) {
            asm volatile("s_waitcnt vmcnt(1)" ::: "memory");
        } else {
            asm volatile("s_waitcnt vmcnt(0)" ::: "memory");
        }
        SBAR();
    }

#undef MFMA16

    // ---- epilogue ----
    const int colb = n0 + wid * 64 + fr * 4;   // 4 consecutive global cols
    const int rbase = m0 + q * 4;

    if (mode == 0) {
        const bool isz = (n0 < H_);
        const float* sc = isz ? zscale : cscale;
        const float* bi = isz ? zbias : cbias;
        unsigned short* dst = isz ? zout : cout;
        const int npb = isz ? colb : colb - H_;
        const float4 s4 = *(const float4*)(sc + npb);
        const float4 b4 = *(const float4*)(bi + npb);
        #pragma unroll
        for (int m = 0; m < 8; ++m)
            #pragma unroll
            for (int r = 0; r < 4; ++r) {
                const int mm = rbase + m * 16 + r;
                float v0 = fmaf(acc[m][0][r], s4.x, b4.x);
                float v1 = fmaf(acc[m][1][r], s4.y, b4.y);
                float v2 = fmaf(acc[m][2][r], s4.z, b4.z);
                float v3 = fmaf(acc[m][3][r], s4.w, b4.w);
                if (isz) {
                    v0 = __builtin_amdgcn_rcpf(1.f + __expf(-v0));
                    v1 = __builtin_amdgcn_rcpf(1.f + __expf(-v1));
                    v2 = __builtin_amdgcn_rcpf(1.f + __expf(-v2));
                    v3 = __builtin_amdgcn_rcpf(1.f + __expf(-v3));
                } else {
                    v0 = fmaxf(v0, 0.f); v1 = fmaxf(v1, 0.f);
                    v2 = fmaxf(v2, 0.f); v3 = fmaxf(v3, 0.f);
                }
                ushort4 pk = make_ushort4(f2b(v0), f2b(v1), f2b(v2), f2b(v3));
                *(ushort4*)(dst + (size_t)mm * H_ + npb) = pk;
            }
    } else {
        const float4 s4 = *(const float4*)(fscale + colb);
        const float4 b4 = *(const float4*)(fbias + colb);
        #pragma unroll
        for (int m = 0; m < 8; ++m)
            #pragma unroll
            for (int r = 0; r < 4; ++r) {
                const int mm = rbase + m * 16 + r;
                ushort4 pk = make_ushort4(
                    f2b(fmaf(acc[m][0][r], s4.x, b4.x)),
                    f2b(fmaf(acc[m][1][r], s4.y, b4.y)),
                    f2b(fmaf(acc[m][2][r], s4.z, b4.z)),
                    f2b(fmaf(acc[m][3][r], s4.w, b4.w)));
                *(ushort4*)(fout + (size_t)mm * OP_ + colb) = pk;
            }
    }
}

// ---------------------------------------------------------------------------
// Scan pass 1: per-chunk (H0, P), h_in = 0.  2 h's per thread (4B loads).
// ---------------------------------------------------------------------------
__global__ __launch_bounds__(256) void scan_pass1(
    const unsigned short* __restrict__ z, const unsigned short* __restrict__ c,
    float* __restrict__ H0, float* __restrict__ P)
{
    const int k = blockIdx.y;
    const int e2 = blockIdx.x * 256 + threadIdx.x;   // pair index < BH_/2
    float h0 = 0.f, h1 = 0.f, p0 = 1.f, p1 = 1.f;
    size_t off = ((size_t)k * TC_ * BH_ + 2 * e2) >> 1;   // in uint units
    const unsigned int* z32 = (const unsigned int*)z;
    const unsigned int* c32 = (const unsigned int*)c;
    #pragma unroll 5
    for (int t = 0; t < TC_; ++t) {
        unsigned int zz = z32[off], cc = c32[off];
        float z0 = b2f((unsigned short)zz), z1 = b2f((unsigned short)(zz >> 16));
        float c0 = b2f((unsigned short)cc), c1 = b2f((unsigned short)(cc >> 16));
        h0 = fmaf(z0, h0 - c0, c0);  p0 *= z0;
        h1 = fmaf(z1, h1 - c1, c1);  p1 *= z1;
        off += BH_ / 2;
    }
    *(float2*)(H0 + (size_t)k * BH_ + 2 * e2) = make_float2(h0, h1);
    *(float2*)(P  + (size_t)k * BH_ + 2 * e2) = make_float2(p0, p1);
}

// ---------------------------------------------------------------------------
// Scan pass 2: fold prior chunk states (exact affine composition), rerun, write x.
// ---------------------------------------------------------------------------
__global__ __launch_bounds__(256) void scan_pass2(
    const unsigned short* __restrict__ z, const unsigned short* __restrict__ c,
    const float* __restrict__ H0, const float* __restrict__ P,
    unsigned short* __restrict__ x)
{
    const int k = blockIdx.y;
    const int e2 = blockIdx.x * 256 + threadIdx.x;
    float h0 = 0.f, h1 = 0.f;
    for (int j = 0; j < k; ++j) {     // k block-uniform: no divergence
        float2 pj = *(const float2*)(P  + (size_t)j * BH_ + 2 * e2);
        float2 hj = *(const float2*)(H0 + (size_t)j * BH_ + 2 * e2);
        h0 = fmaf(pj.x, h0, hj.x);
        h1 = fmaf(pj.y, h1, hj.y);
    }
    size_t off = ((size_t)k * TC_ * BH_ + 2 * e2) >> 1;
    const unsigned int* z32 = (const unsigned int*)z;
    const unsigned int* c32 = (const unsigned int*)c;
    unsigned int* x32 = (unsigned int*)x;
    #pragma unroll 5
    for (int t = 0; t < TC_; ++t) {
        unsigned int zz = z32[off], cc = c32[off];
        float z0 = b2f((unsigned short)zz), z1 = b2f((unsigned short)(zz >> 16));
        float c0 = b2f((unsigned short)cc), c1 = b2f((unsigned short)(cc >> 16));
        h0 = fmaf(z0, h0 - c0, c0);
        h1 = fmaf(z1, h1 - c1, c1);
        x32[off] = (unsigned int)f2b(h0) | ((unsigned int)f2b(h1) << 16);
        off += BH_ / 2;
    }
}

// ---------------------------------------------------------------------------
// row-wise log_softmax: bf16 logits [M x OP_] -> fp32 out [M x O_]
// ---------------------------------------------------------------------------
__global__ __launch_bounds__(256) void logsoftmax_kernel(
    const unsigned short* __restrict__ lg, float* __restrict__ out)
{
    const int row = blockIdx.x;
    const unsigned short* p = lg + (size_t)row * OP_;
    float* po = out + (size_t)row * O_;
    const int tid = threadIdx.x;

    float v[8];
    float mx = -1e30f;
    #pragma unroll
    for (int j = 0; j < 8; j++) {
        int col = tid + j * 256;
        v[j] = (col < O_) ? b2f(p[col]) : -1e30f;
        mx = fmaxf(mx, v[j]);
    }
    #pragma unroll
    for (int o = 32; o > 0; o >>= 1) mx = fmaxf(mx, __shfl_down(mx, o));
    __shared__ float smax[4];
    __shared__ float ssum[4];
    const int lane = tid & 63, wid = tid >> 6;
    if (lane == 0) smax[wid] = mx;
    __syncthreads();
    mx = fmaxf(fmaxf(smax[0], smax[1]), fmaxf(smax[2], smax[3]));

    float s = 0.f;
    #pragma unroll
    for (int j = 0; j < 8; j++) {
        int col = tid + j * 256;
        if (col < O_) s += expf(v[j] - mx);
    }
    #pragma unroll
    for (int o = 32; o > 0; o >>= 1) s += __shfl_down(s, o);
    if (lane == 0) ssum[wid] = s;
    __syncthreads();
    s = ssum[0] + ssum[1] + ssum[2] + ssum[3];
    const float lse = mx + logf(s);

    #pragma unroll
    for (int j = 0; j < 8; j++) {
        int col = tid + j * 256;
        if (col < O_) po[col] = v[j] - lse;
    }
}

// ---------------------------------------------------------------------------
extern "C" void kernel_launch(void* const* d_in, const int* in_sizes, int n_in,
                              void* d_out, int out_size, void* d_ws, size_t ws_size,
                              hipStream_t stream)
{
    (void)in_sizes; (void)n_in; (void)out_size; (void)ws_size;

    const float* xs    = (const float*)d_in[0];
    const float* w0    = (const float*)d_in[1];
    const float* wr    = (const float*)d_in[2];
    const float* bnz_g = (const float*)d_in[3];
    const float* bnz_b = (const float*)d_in[4];
    const float* bnz_m = (const float*)d_in[5];
    const float* bnz_v = (const float*)d_in[6];
    const float* bnc_g = (const float*)d_in[7];
    const float* bnc_b = (const float*)d_in[8];
    const float* bnc_m = (const float*)d_in[9];
    const float* bnc_v = (const float*)d_in[10];
    const float* wf    = (const float*)d_in[11];
    const float* bnf_g = (const float*)d_in[12];
    const float* bnf_b = (const float*)d_in[13];
    const float* bnf_m = (const float*)d_in[14];
    const float* bnf_v = (const float*)d_in[15];
    float* out = (float*)d_out;

    unsigned short* p = (unsigned short*)d_ws;
    unsigned short* xbuf  = p;  p += (size_t)M_ * H_;
    unsigned short* x0buf = p;  p += (size_t)M_ * DP_;
    unsigned short* zbuf  = p;  p += (size_t)M_ * H_;
    unsigned short* cbuf  = p;  p += (size_t)M_ * H_;
    unsigned short* w0p   = p;  p += (size_t)(2 * H_) * DP_;
    unsigned short* wrp   = p;  p += (size_t)(L_ - 1) * (2 * H_) * H_;
    unsigned short* wfp   = p;  p += (size_t)OP_ * H_;
    unsigned short* lbuf  = p;  p += (size_t)M_ * OP_;
    float* fp = (float*)p;
    float* zs = fp;  fp += L_ * H_;
    float* zb = fp;  fp += L_ * H_;
    float* cs = fp;  fp += L_ * H_;
    float* cb = fp;  fp += L_ * H_;
    float* fs = fp;  fp += OP_;
    float* fb = fp;  fp += OP_;
    float* sH0 = fp; fp += NC_ * BH_;
    float* sP  = fp;

    dim3 blk(256);
    bn_prep<<<(L_ * H_ + 255) / 256, blk, 0, stream>>>(bnz_g, bnz_b, bnz_m, bnz_v, zs, zb, L_ * H_, L_ * H_);
    bn_prep<<<(L_ * H_ + 255) / 256, blk, 0, stream>>>(bnc_g, bnc_b, bnc_m, bnc_v, cs, cb, L_ * H_, L_ * H_);
    bn_prep<<<(OP_ + 255) / 256, blk, 0, stream>>>(bnf_g, bnf_b, bnf_m, bnf_v, fs, fb, O_, OP_);

    {   // bf16 conversions with padding (all shapes satisfy Cs%8==0, 16B rows)
        int t0 = M_ * DP_ / 8;
        cvt_pad8<<<(t0 + 255) / 256, blk, 0, stream>>>(xs, x0buf, M_, D_, DP_, t0);
        int t1 = 2 * H_ * DP_ / 8;
        cvt_pad8<<<(t1 + 255) / 256, blk, 0, stream>>>(w0, w0p, 2 * H_, D_, DP_, t1);
        int t2 = (L_ - 1) * 2 * H_ * H_ / 8;
        cvt_pad8<<<(t2 + 255) / 256, blk, 0, stream>>>(wr, wrp, (L_ - 1) * 2 * H_, H_, H_, t2);
        int t3 = OP_ * H_ / 8;
        cvt_pad8<<<(t3 + 255) / 256, blk, 0, stream>>>(wf, wfp, O_, H_, H_, t3);
    }

    dim3 blk2(256);
    dim3 grid2((M_ / BM2) * ((2 * H_) / BN2));    // 200 * 8 = 1600
    dim3 sgrid1(BH_ / 512, NC_ - 1);
    dim3 sgrid2(BH_ / 512, NC_);
    for (int layer = 0; layer < L_; ++layer) {
        const unsigned short* Ain = (layer == 0) ? x0buf : xbuf;
        const unsigned short* W   = (layer == 0) ? w0p : (wrp + (size_t)(layer - 1) * (2 * H_) * H_);
        const int K               = (layer == 0) ? DP_ : H_;
        gemm_bf16<<<grid2, blk2, 0, stream>>>(Ain, W, K, 0,
            zbuf, cbuf,
            zs + layer * H_, zb + layer * H_, cs + layer * H_, cb + layer * H_,
            nullptr, nullptr, nullptr);
        scan_pass1<<<sgrid1, blk, 0, stream>>>(zbuf, cbuf, sH0, sP);
        scan_pass2<<<sgrid2, blk, 0, stream>>>(zbuf, cbuf, sH0, sP, xbuf);
    }

    dim3 gridf((M_ / BM2) * (OP_ / BN2));         // 200 * 8 = 1600
    gemm_bf16<<<gridf, blk2, 0, stream>>>(xbuf, wfp, H_, 1,
        nullptr, nullptr, nullptr, nullptr, nullptr, nullptr,
        lbuf, fs, fb);

    logsoftmax_kernel<<<M_, blk, 0, stream>>>(lbuf, out);
}

// Round 6
// 1072.740 us; speedup vs baseline: 1.0623x; 1.0450x over previous
//
#include <hip/hip_runtime.h>
#include <math.h>
#include <stdint.h>

#define T_ 800
#define B_ 32
#define D_ 440
#define DP_ 448      // D padded to mult of 32
#define H_ 1024
#define L_ 4
#define O_ 2000
#define OP_ 2048     // O padded to mult of 256
#define EPS_ 1e-5f
#define M_ (T_ * B_)   // 25600
#define BH_ (B_ * H_)  // 32768
#define NC_ 16
#define TC_ (T_ / NC_) // 50

// 128x256x32 4-wave GEMM geometry, 2 blocks/CU
#define BM2 128
#define BN2 256
#define BK2 32

typedef __attribute__((ext_vector_type(8))) short bf16x8;
typedef __attribute__((ext_vector_type(4))) float f32x4;

__device__ inline float b2f(unsigned short u) {
    union { unsigned int i; float f; } v; v.i = ((unsigned int)u) << 16; return v.f;
}
__device__ inline unsigned short f2b(float f) {   // RNE bf16 (finite only)
    unsigned int x = __float_as_uint(f);
    return (unsigned short)((x + 0x7FFFu + ((x >> 16) & 1u)) >> 16);
}

// ---------------------------------------------------------------------------
// BN fold with dst padding: y = x*scale + bias; i >= nsrc -> 0
// ---------------------------------------------------------------------------
__global__ void bn_prep(const float* __restrict__ g, const float* __restrict__ b,
                        const float* __restrict__ m, const float* __restrict__ v,
                        float* __restrict__ scale, float* __restrict__ bias,
                        int nsrc, int ndst)
{
    int i = blockIdx.x * 256 + threadIdx.x;
    if (i >= ndst) return;
    if (i < nsrc) {
        float s = g[i] * rsqrtf(v[i] + EPS_);
        scale[i] = s;
        bias[i] = fmaf(-m[i], s, b[i]);
    } else {
        scale[i] = 0.f;
        bias[i] = 0.f;
    }
}

// ---------------------------------------------------------------------------
// fp32 [Rs x Cs] -> bf16 [Rd x Cd], 8 cols per thread.
// ---------------------------------------------------------------------------
__global__ void cvt_pad8(const float* __restrict__ src, unsigned short* __restrict__ dst,
                         int Rs, int Cs, int Cd, int total8)
{
    int i = blockIdx.x * 256 + threadIdx.x;
    if (i >= total8) return;
    const int c8 = Cd >> 3;
    int r = i / c8, c = (i - r * c8) << 3;
    ushort4 lo, hi;
    if (r < Rs && c < Cs) {
        const float4 a = *(const float4*)(src + (size_t)r * Cs + c);
        const float4 b = *(const float4*)(src + (size_t)r * Cs + c + 4);
        lo = make_ushort4(f2b(a.x), f2b(a.y), f2b(a.z), f2b(a.w));
        hi = make_ushort4(f2b(b.x), f2b(b.y), f2b(b.z), f2b(b.w));
    } else {
        lo = make_ushort4(0, 0, 0, 0);
        hi = make_ushort4(0, 0, 0, 0);
    }
    unsigned short* d = dst + (size_t)r * Cd + c;
    *(ushort4*)d = lo;
    *(ushort4*)(d + 4) = hi;
}

// ---------------------------------------------------------------------------
// bf16 NT GEMM, 128x256x32 tiles, 4 waves (1M x 4N), 2 blocks/CU.
// Schedule identical to the harness-verified round-4 kernel (2 phases/K-tile,
// counted vmcnt(6), GLDS staging, column-interleaved B, ushort4 epilogue).
//
// XCD-aware block remap pins *M-panels* (A) to XCDs instead of N-panels:
//   g = 64*(m/8) + 8*n + (m%8)  (bijective; 200 M-tiles, 8 N-tiles)
//   hardware round-robins g%8 -> XCD, so XCD x owns all m = x (mod 8):
//   the 256 KB A-panel is fetched ONCE per XCD and shared by its 8 N-tile
//   blocks in L2; B (4.2 MB) becomes ~L2-resident per XCD. Rounds 2/4 tied
//   at 153.6 us with FETCH 213 MB (A streamed by every XCD => every A load
//   an L2 miss, ~900 cyc, deeper than the 2-phase prefetch): this remap
//   attacks both the over-fetch and the first-touch latency exposure.
// mode 0: n<H -> z=sigmoid(bn), else c=relu(bn); bf16 [M x H]
// mode 1: logits bf16 [M x OP_], bn affine only
// ---------------------------------------------------------------------------

#define GLDS16(src, dst) __builtin_amdgcn_global_load_lds( \
    (const __attribute__((address_space(1))) unsigned int*)(src), \
    (__attribute__((address_space(3))) unsigned int*)(dst), 16, 0, 0)

#define SBAR() __builtin_amdgcn_s_barrier()
#define LGKM0() do { asm volatile("s_waitcnt lgkmcnt(0)" ::: "memory"); \
                     __builtin_amdgcn_sched_barrier(0); } while (0)

__global__ __launch_bounds__(256, 2) void gemm_bf16(
    const unsigned short* __restrict__ A, const unsigned short* __restrict__ Wt,
    int K, int mode,
    unsigned short* __restrict__ zout, unsigned short* __restrict__ cout,
    const float* __restrict__ zscale, const float* __restrict__ zbias,
    const float* __restrict__ cscale, const float* __restrict__ cbias,
    unsigned short* __restrict__ fout,
    const float* __restrict__ fscale, const float* __restrict__ fbias)
{
    // A: [2 buf][128 rows x 32]  = 16 KB ; B: [2 buf][256 slots x 32] = 32 KB
    __shared__ unsigned short As[2][128 * 32];
    __shared__ unsigned short Bs[2][256 * 32];

    const int tid = threadIdx.x;
    const int lane = tid & 63;
    const int wid = tid >> 6;            // 0..3 = N quarter (cols wid*64..)

    // XCD-aware decode: g = 64*(m/8) + 8*n + (m%8); XCD(g)=g%8=m%8 pins A.
    const int g = blockIdx.x;
    const int n_t = (g >> 3) & 7;                 // N tile 0..7
    const int m_t = ((g >> 6) << 3) | (g & 7);    // M tile 0..199
    const int m0 = m_t * BM2;
    const int n0 = n_t * BN2;

    // ---- staging sources (linear; GLDS slot = 16 rows x 64B, lane l covers
    // row (l>>2), bytes (l&3)*16 of the 64B row) ----
    const int srow = lane >> 2;          // 0..15
    const int scol = (lane & 3) * 8;     // elem offset in 32-elem row

    const unsigned short* aE = A + (size_t)(m0 + wid * 16 + srow) * K + scol;       // A rows 0-63, slot wid
    const unsigned short* aL = A + (size_t)(m0 + 64 + wid * 16 + srow) * K + scol;  // A rows 64-127, slot 4+wid
    // B stage slots S = wid*4+i: gcol = n0 + wid*64 + srow*4 + i
    const unsigned short* bS0 = Wt + (size_t)(n0 + wid * 64 + srow * 4 + 0) * K + scol;
    const unsigned short* bS1 = Wt + (size_t)(n0 + wid * 64 + srow * 4 + 1) * K + scol;
    const unsigned short* bS2 = Wt + (size_t)(n0 + wid * 64 + srow * 4 + 2) * K + scol;
    const unsigned short* bS3 = Wt + (size_t)(n0 + wid * 64 + srow * 4 + 3) * K + scol;

    const int lsAE = wid * 512;          // LDS elem offsets (wave-uniform)
    const int lsAL = (4 + wid) * 512;
    const int lsB0 = (wid * 4 + 0) * 512;
    const int lsB1 = (wid * 4 + 1) * 512;
    const int lsB2 = (wid * 4 + 2) * 512;
    const int lsB3 = (wid * 4 + 3) * 512;

    // ---- fragment read addressing (linear) ----
    const int fr = lane & 15;
    const int q = lane >> 4;
    const int rdc = q * 8;

    f32x4 acc[8][4];
    #pragma unroll
    for (int i = 0; i < 8; i++)
        #pragma unroll
        for (int j = 0; j < 4; j++)
            acc[i][j] = (f32x4){0.f, 0.f, 0.f, 0.f};

    bf16x8 af[4], bfv[4];

    const int nT = K / BK2;

    // ---- prologue (FIFO order: e(0) [5], l(0) [1], e(1) [5]) ----
    GLDS16(aE,  &As[0][lsAE]);
    GLDS16(bS0, &Bs[0][lsB0]); GLDS16(bS1, &Bs[0][lsB1]);
    GLDS16(bS2, &Bs[0][lsB2]); GLDS16(bS3, &Bs[0][lsB3]);
    GLDS16(aL,  &As[0][lsAL]);
    if (nT > 1) {
        GLDS16(aE + BK2,  &As[1][lsAE]);
        GLDS16(bS0 + BK2, &Bs[1][lsB0]); GLDS16(bS1 + BK2, &Bs[1][lsB1]);
        GLDS16(bS2 + BK2, &Bs[1][lsB2]); GLDS16(bS3 + BK2, &Bs[1][lsB3]);
        asm volatile("s_waitcnt vmcnt(6)" ::: "memory");   // drain e(0)
    } else {
        asm volatile("s_waitcnt vmcnt(1)" ::: "memory");
    }
    SBAR();

#define MFMA16(MBASE) do { \
    __builtin_amdgcn_s_setprio(1); \
    _Pragma("unroll") \
    for (int m_ = 0; m_ < 4; ++m_) \
        _Pragma("unroll") \
        for (int n_ = 0; n_ < 4; ++n_) \
            acc[MBASE + m_][n_] = __builtin_amdgcn_mfma_f32_16x16x32_bf16( \
                af[m_], bfv[n_], acc[MBASE + m_][n_], 0, 0, 0); \
    __builtin_amdgcn_s_setprio(0); \
} while (0)

    for (int t = 0; t < nT; ++t) {
        const int cur = t & 1, nxt = cur ^ 1;
        const unsigned short* Ac = As[cur];
        const unsigned short* Bc = Bs[cur] + wid * (64 * 32);
        const int kL = (t + 1) * BK2;
        const int kE = (t + 2) * BK2;

        // ---- phase A: rows 0-63, all B; stage l(t+1) ----
        #pragma unroll
        for (int m_ = 0; m_ < 4; ++m_)
            af[m_] = *(const bf16x8*)(Ac + (m_ * 16 + fr) * 32 + rdc);
        #pragma unroll
        for (int n_ = 0; n_ < 4; ++n_)
            bfv[n_] = *(const bf16x8*)(Bc + (n_ * 16 + fr) * 32 + rdc);
        if (t + 1 < nT) {
            GLDS16(aL + kL, &As[nxt][lsAL]);
        }
        SBAR();
        LGKM0();
        MFMA16(0);
        if (t + 1 < nT) {                      // drain l(t) before P_B reads
            asm volatile("s_waitcnt vmcnt(6)" ::: "memory");
        } else {
            asm volatile("s_waitcnt vmcnt(0)" ::: "memory");
        }
        SBAR();

        // ---- phase B: rows 64-127; stage e(t+2) (buffer cur: rows 0-63 and
        // all B of cur were last read in phase A, done at its barrier) ----
        #pragma unroll
        for (int m_ = 0; m_ < 4; ++m_)
            af[m_] = *(const bf16x8*)(Ac + ((4 + m_) * 16 + fr) * 32 + rdc);
        if (t + 2 < nT) {
            GLDS16(aE + kE,  &As[cur][lsAE]);
            GLDS16(bS0 + kE, &Bs[cur][lsB0]); GLDS16(bS1 + kE, &Bs[cur][lsB1]);
            GLDS16(bS2 + kE, &Bs[cur][lsB2]); GLDS16(bS3 + kE, &Bs[cur][lsB3]);
        }
        SBAR();
        LGKM0();
        MFMA16(4);
        if (t + 2 < nT) {                      // drain e(t+1) before next P_A
            asm volatile("s_waitcnt vmcnt(6)" ::: "memory");
        } else if (t + 1 < nT) {
            asm volatile("s_waitcnt vmcnt(1)" ::: "memory");
        } else {
            asm volatile("s_waitcnt vmcnt(0)" ::: "memory");
        }
        SBAR();
    }

#undef MFMA16

    // ---- epilogue ----
    const int colb = n0 + wid * 64 + fr * 4;   // 4 consecutive global cols
    const int rbase = m0 + q * 4;

    if (mode == 0) {
        const bool isz = (n0 < H_);
        const float* sc = isz ? zscale : cscale;
        const float* bi = isz ? zbias : cbias;
        unsigned short* dst = isz ? zout : cout;
        const int npb = isz ? colb : colb - H_;
        const float4 s4 = *(const float4*)(sc + npb);
        const float4 b4 = *(const float4*)(bi + npb);
        #pragma unroll
        for (int m = 0; m < 8; ++m)
            #pragma unroll
            for (int r = 0; r < 4; ++r) {
                const int mm = rbase + m * 16 + r;
                float v0 = fmaf(acc[m][0][r], s4.x, b4.x);
                float v1 = fmaf(acc[m][1][r], s4.y, b4.y);
                float v2 = fmaf(acc[m][2][r], s4.z, b4.z);
                float v3 = fmaf(acc[m][3][r], s4.w, b4.w);
                if (isz) {
                    v0 = __builtin_amdgcn_rcpf(1.f + __expf(-v0));
                    v1 = __builtin_amdgcn_rcpf(1.f + __expf(-v1));
                    v2 = __builtin_amdgcn_rcpf(1.f + __expf(-v2));
                    v3 = __builtin_amdgcn_rcpf(1.f + __expf(-v3));
                } else {
                    v0 = fmaxf(v0, 0.f); v1 = fmaxf(v1, 0.f);
                    v2 = fmaxf(v2, 0.f); v3 = fmaxf(v3, 0.f);
                }
                ushort4 pk = make_ushort4(f2b(v0), f2b(v1), f2b(v2), f2b(v3));
                *(ushort4*)(dst + (size_t)mm * H_ + npb) = pk;
            }
    } else {
        const float4 s4 = *(const float4*)(fscale + colb);
        const float4 b4 = *(const float4*)(fbias + colb);
        #pragma unroll
        for (int m = 0; m < 8; ++m)
            #pragma unroll
            for (int r = 0; r < 4; ++r) {
                const int mm = rbase + m * 16 + r;
                ushort4 pk = make_ushort4(
                    f2b(fmaf(acc[m][0][r], s4.x, b4.x)),
                    f2b(fmaf(acc[m][1][r], s4.y, b4.y)),
                    f2b(fmaf(acc[m][2][r], s4.z, b4.z)),
                    f2b(fmaf(acc[m][3][r], s4.w, b4.w)));
                *(ushort4*)(fout + (size_t)mm * OP_ + colb) = pk;
            }
    }
}

// ---------------------------------------------------------------------------
// Scan pass 1: per-chunk (H0, P), h_in = 0.  2 h's per thread (4B loads).
// ---------------------------------------------------------------------------
__global__ __launch_bounds__(256) void scan_pass1(
    const unsigned short* __restrict__ z, const unsigned short* __restrict__ c,
    float* __restrict__ H0, float* __restrict__ P)
{
    const int k = blockIdx.y;
    const int e2 = blockIdx.x * 256 + threadIdx.x;   // pair index < BH_/2
    float h0 = 0.f, h1 = 0.f, p0 = 1.f, p1 = 1.f;
    size_t off = ((size_t)k * TC_ * BH_ + 2 * e2) >> 1;   // in uint units
    const unsigned int* z32 = (const unsigned int*)z;
    const unsigned int* c32 = (const unsigned int*)c;
    #pragma unroll 5
    for (int t = 0; t < TC_; ++t) {
        unsigned int zz = z32[off], cc = c32[off];
        float z0 = b2f((unsigned short)zz), z1 = b2f((unsigned short)(zz >> 16));
        float c0 = b2f((unsigned short)cc), c1 = b2f((unsigned short)(cc >> 16));
        h0 = fmaf(z0, h0 - c0, c0);  p0 *= z0;
        h1 = fmaf(z1, h1 - c1, c1);  p1 *= z1;
        off += BH_ / 2;
    }
    *(float2*)(H0 + (size_t)k * BH_ + 2 * e2) = make_float2(h0, h1);
    *(float2*)(P  + (size_t)k * BH_ + 2 * e2) = make_float2(p0, p1);
}

// ---------------------------------------------------------------------------
// Scan pass 2: fold prior chunk states (exact affine composition), rerun, write x.
// ---------------------------------------------------------------------------
__global__ __launch_bounds__(256) void scan_pass2(
    const unsigned short* __restrict__ z, const unsigned short* __restrict__ c,
    const float* __restrict__ H0, const float* __restrict__ P,
    unsigned short* __restrict__ x)
{
    const int k = blockIdx.y;
    const int e2 = blockIdx.x * 256 + threadIdx.x;
    float h0 = 0.f, h1 = 0.f;
    for (int j = 0; j < k; ++j) {     // k block-uniform: no divergence
        float2 pj = *(const float2*)(P  + (size_t)j * BH_ + 2 * e2);
        float2 hj = *(const float2*)(H0 + (size_t)j * BH_ + 2 * e2);
        h0 = fmaf(pj.x, h0, hj.x);
        h1 = fmaf(pj.y, h1, hj.y);
    }
    size_t off = ((size_t)k * TC_ * BH_ + 2 * e2) >> 1;
    const unsigned int* z32 = (const unsigned int*)z;
    const unsigned int* c32 = (const unsigned int*)c;
    unsigned int* x32 = (unsigned int*)x;
    #pragma unroll 5
    for (int t = 0; t < TC_; ++t) {
        unsigned int zz = z32[off], cc = c32[off];
        float z0 = b2f((unsigned short)zz), z1 = b2f((unsigned short)(zz >> 16));
        float c0 = b2f((unsigned short)cc), c1 = b2f((unsigned short)(cc >> 16));
        h0 = fmaf(z0, h0 - c0, c0);
        h1 = fmaf(z1, h1 - c1, c1);
        x32[off] = (unsigned int)f2b(h0) | ((unsigned int)f2b(h1) << 16);
        off += BH_ / 2;
    }
}

// ---------------------------------------------------------------------------
// row-wise log_softmax: bf16 logits [M x OP_] -> fp32 out [M x O_]
// ---------------------------------------------------------------------------
__global__ __launch_bounds__(256) void logsoftmax_kernel(
    const unsigned short* __restrict__ lg, float* __restrict__ out)
{
    const int row = blockIdx.x;
    const unsigned short* p = lg + (size_t)row * OP_;
    float* po = out + (size_t)row * O_;
    const int tid = threadIdx.x;

    float v[8];
    float mx = -1e30f;
    #pragma unroll
    for (int j = 0; j < 8; j++) {
        int col = tid + j * 256;
        v[j] = (col < O_) ? b2f(p[col]) : -1e30f;
        mx = fmaxf(mx, v[j]);
    }
    #pragma unroll
    for (int o = 32; o > 0; o >>= 1) mx = fmaxf(mx, __shfl_down(mx, o));
    __shared__ float smax[4];
    __shared__ float ssum[4];
    const int lane = tid & 63, wid = tid >> 6;
    if (lane == 0) smax[wid] = mx;
    __syncthreads();
    mx = fmaxf(fmaxf(smax[0], smax[1]), fmaxf(smax[2], smax[3]));

    float s = 0.f;
    #pragma unroll
    for (int j = 0; j < 8; j++) {
        int col = tid + j * 256;
        if (col < O_) s += expf(v[j] - mx);
    }
    #pragma unroll
    for (int o = 32; o > 0; o >>= 1) s += __shfl_down(s, o);
    if (lane == 0) ssum[wid] = s;
    __syncthreads();
    s = ssum[0] + ssum[1] + ssum[2] + ssum[3];
    const float lse = mx + logf(s);

    #pragma unroll
    for (int j = 0; j < 8; j++) {
        int col = tid + j * 256;
        if (col < O_) po[col] = v[j] - lse;
    }
}

// ---------------------------------------------------------------------------
extern "C" void kernel_launch(void* const* d_in, const int* in_sizes, int n_in,
                              void* d_out, int out_size, void* d_ws, size_t ws_size,
                              hipStream_t stream)
{
    (void)in_sizes; (void)n_in; (void)out_size; (void)ws_size;

    const float* xs    = (const float*)d_in[0];
    const float* w0    = (const float*)d_in[1];
    const float* wr    = (const float*)d_in[2];
    const float* bnz_g = (const float*)d_in[3];
    const float* bnz_b = (const float*)d_in[4];
    const float* bnz_m = (const float*)d_in[5];
    const float* bnz_v = (const float*)d_in[6];
    const float* bnc_g = (const float*)d_in[7];
    const float* bnc_b = (const float*)d_in[8];
    const float* bnc_m = (const float*)d_in[9];
    const float* bnc_v = (const float*)d_in[10];
    const float* wf    = (const float*)d_in[11];
    const float* bnf_g = (const float*)d_in[12];
    const float* bnf_b = (const float*)d_in[13];
    const float* bnf_m = (const float*)d_in[14];
    const float* bnf_v = (const float*)d_in[15];
    float* out = (float*)d_out;

    unsigned short* p = (unsigned short*)d_ws;
    unsigned short* xbuf  = p;  p += (size_t)M_ * H_;
    unsigned short* x0buf = p;  p += (size_t)M_ * DP_;
    unsigned short* zbuf  = p;  p += (size_t)M_ * H_;
    unsigned short* cbuf  = p;  p += (size_t)M_ * H_;
    unsigned short* w0p   = p;  p += (size_t)(2 * H_) * DP_;
    unsigned short* wrp   = p;  p += (size_t)(L_ - 1) * (2 * H_) * H_;
    unsigned short* wfp   = p;  p += (size_t)OP_ * H_;
    unsigned short* lbuf  = p;  p += (size_t)M_ * OP_;
    float* fp = (float*)p;
    float* zs = fp;  fp += L_ * H_;
    float* zb = fp;  fp += L_ * H_;
    float* cs = fp;  fp += L_ * H_;
    float* cb = fp;  fp += L_ * H_;
    float* fs = fp;  fp += OP_;
    float* fb = fp;  fp += OP_;
    float* sH0 = fp; fp += NC_ * BH_;
    float* sP  = fp;

    dim3 blk(256);
    bn_prep<<<(L_ * H_ + 255) / 256, blk, 0, stream>>>(bnz_g, bnz_b, bnz_m, bnz_v, zs, zb, L_ * H_, L_ * H_);
    bn_prep<<<(L_ * H_ + 255) / 256, blk, 0, stream>>>(bnc_g, bnc_b, bnc_m, bnc_v, cs, cb, L_ * H_, L_ * H_);
    bn_prep<<<(OP_ + 255) / 256, blk, 0, stream>>>(bnf_g, bnf_b, bnf_m, bnf_v, fs, fb, O_, OP_);

    {   // bf16 conversions with padding (all shapes satisfy Cs%8==0, 16B rows)
        int t0 = M_ * DP_ / 8;
        cvt_pad8<<<(t0 + 255) / 256, blk, 0, stream>>>(xs, x0buf, M_, D_, DP_, t0);
        int t1 = 2 * H_ * DP_ / 8;
        cvt_pad8<<<(t1 + 255) / 256, blk, 0, stream>>>(w0, w0p, 2 * H_, D_, DP_, t1);
        int t2 = (L_ - 1) * 2 * H_ * H_ / 8;
        cvt_pad8<<<(t2 + 255) / 256, blk, 0, stream>>>(wr, wrp, (L_ - 1) * 2 * H_, H_, H_, t2);
        int t3 = OP_ * H_ / 8;
        cvt_pad8<<<(t3 + 255) / 256, blk, 0, stream>>>(wf, wfp, O_, H_, H_, t3);
    }

    dim3 blk2(256);
    dim3 grid2((M_ / BM2) * ((2 * H_) / BN2));    // 200 * 8 = 1600
    dim3 sgrid1(BH_ / 512, NC_ - 1);
    dim3 sgrid2(BH_ / 512, NC_);
    for (int layer = 0; layer < L_; ++layer) {
        const unsigned short* Ain = (layer == 0) ? x0buf : xbuf;
        const unsigned short* W   = (layer == 0) ? w0p : (wrp + (size_t)(layer - 1) * (2 * H_) * H_);
        const int K               = (layer == 0) ? DP_ : H_;
        gemm_bf16<<<grid2, blk2, 0, stream>>>(Ain, W, K, 0,
            zbuf, cbuf,
            zs + layer * H_, zb + layer * H_, cs + layer * H_, cb + layer * H_,
            nullptr, nullptr, nullptr);
        scan_pass1<<<sgrid1, blk, 0, stream>>>(zbuf, cbuf, sH0, sP);
        scan_pass2<<<sgrid2, blk, 0, stream>>>(zbuf, cbuf, sH0, sP, xbuf);
    }

    dim3 gridf((M_ / BM2) * (OP_ / BN2));         // 200 * 8 = 1600
    gemm_bf16<<<gridf, blk2, 0, stream>>>(xbuf, wfp, H_, 1,
        nullptr, nullptr, nullptr, nullptr, nullptr, nullptr,
        lbuf, fs, fb);

    logsoftmax_kernel<<<M_, blk, 0, stream>>>(lbuf, out);
}